// Round 6
// baseline (289.505 us; speedup 1.0000x reference)
//
#include <hip/hip_runtime.h>
#include <stdint.h>

// GatingLayer fused kernel, R9.
// logits = x[16384,3072] . W[8,3072]^T + b[8]; softmax(8); top-2 (stable,
// lowest-index tie-break); softmax over the selected 2.
// d_out = values (fp32 x 32768) ++ indices-as-float (x 32768).
//
// R9 = R8's theory (W thrashes L1/L2: 96 KB > 32 KB L1, 50% of VMEM
// instrs; barrier-free waves drift so per-stage W windows re-fetch from
// L2 at ~the L2 ceiling on top of the x stream) WITHOUT R8's risky
// >64 KB dynamic-LDS path (hipFuncSetAttribute inside graph capture is
// the prime suspect for the container failure). W is staged in TWO
// 48 KB static-LDS halves: all 12 W float4 loads issue in the PROLOGUE
// (oldest in vmcnt order -> waiting on them never drains x); half 1
// parks in 24 VGPRs until the mid-kernel restage. 3 barriers total
// (prologue, pre/post restage) vs R5's 13.
//
// Geometry: TPB=512 (8 waves), 48 KB LDS -> 2 blocks/CU, 16 waves/CU
// (same as R7: single-variable test of the W-path theory). TOKW=4 ->
// 32 tokens/block, grid 512. Lane map (R7's): lane = sl*2 + tg;
// sl in [0,32) = 16B d-slice of a 128-float stage; tg = expert half.
// acc[4][4]; x register ping-pong clumps xa/xb; compute(i) consumes
// only clump-i regs (older than clump i+1 in vmcnt order).
// LDS layout: sw4[s_local*256 + e*32 + q] float4 -> wave reads 512 B
// contiguous per expert slice, tg pairs broadcast; bandwidth-limited
// only (standard GEMM fragment pattern).

#define NTOK   16384
#define DMODEL 3072
#define NEXP   8
#define TPB    512              // 8 waves
#define NWAVE  (TPB / 64)
#define TOKW   4                // tokens per wave
#define TOKB   (NWAVE * TOKW)   // 32 tokens per block
#define STF    128              // floats of d per stage
#define NST    (DMODEL / STF)   // 24 stages
#define HALF   (NST / 2)        // 12 stages per LDS half
#define W4H    (NEXP * HALF * 32)   // 3072 float4 = 48 KB per half
#define W4PT   (W4H / TPB)          // 6 float4 per thread per half

#define GATE_COMPUTE(WR, XR)                                          \
  {                                                                   \
    _Pragma("unroll")                                                 \
    for (int p = 0; p < TOKW; ++p) {                                  \
      const float4 xv = XR[p];                                        \
      _Pragma("unroll")                                               \
      for (int e = 0; e < 4; ++e)                                     \
        acc[p][e] = fmaf(xv.x, WR[e].x,                               \
                    fmaf(xv.y, WR[e].y,                               \
                    fmaf(xv.z, WR[e].z,                               \
                    fmaf(xv.w, WR[e].w, acc[p][e]))));                \
    }                                                                 \
  }

// One ping-pong iteration: LDS stage index SL (local), x stage index S
// (global). Consumes xa for stage S, xb for S+1; prefetches S+2 into xa.
#define GATE_ITER(SL, S)                                              \
  {                                                                   \
    _Pragma("unroll")                                                 \
    for (int p = 0; p < TOKW; ++p)                                    \
      xb[p] = *(const float4*)(px[p] + ((S) + 1) * STF);              \
    float4 w4[4];                                                     \
    _Pragma("unroll")                                                 \
    for (int e = 0; e < 4; ++e)                                       \
      w4[e] = sw4[(SL) * 256 + (tg * 4 + e) * 32 + sl];               \
    GATE_COMPUTE(w4, xa);                                             \
    if ((S) + 2 < NST) {                                              \
      _Pragma("unroll")                                               \
      for (int p = 0; p < TOKW; ++p)                                  \
        xa[p] = *(const float4*)(px[p] + ((S) + 2) * STF);            \
    }                                                                 \
    _Pragma("unroll")                                                 \
    for (int e = 0; e < 4; ++e)                                       \
      w4[e] = sw4[((SL) + 1) * 256 + (tg * 4 + e) * 32 + sl];         \
    GATE_COMPUTE(w4, xb);                                             \
  }

__global__ __launch_bounds__(TPB, 4) void gate_fused6(
    const float* __restrict__ x, const float* __restrict__ W,
    const float* __restrict__ bias, float* __restrict__ out) {
  __shared__ float4 sw4[W4H];   // 48 KB: one W half [12][8][32] float4

  const int tid  = threadIdx.x;
  const int wv   = tid >> 6;
  const int lane = tid & 63;
  const int tg   = lane & 1;        // expert half
  const int sl   = lane >> 1;       // d-slice [0,32)
  const int tokBase = blockIdx.x * TOKB + wv * TOKW;

  const float4* Wf4 = (const float4*)W;

  // ---- prologue: ALL W loads first (oldest in vmcnt order) ----
  float4 wrA[W4PT], wrB[W4PT];
#pragma unroll
  for (int k = 0; k < W4PT; ++k) {
    const int L = tid + k * TPB;        // [0, 3072)
    const int e = L / 384, r = L - e * 384;
    wrA[k] = Wf4[e * 768 + r];          // half 0 (stages 0..11)
  }
#pragma unroll
  for (int k = 0; k < W4PT; ++k) {
    const int L = tid + k * TPB;
    const int e = L / 384, r = L - e * 384;
    wrB[k] = Wf4[e * 768 + 384 + r];    // half 1 (stages 12..23)
  }

  // x pointers + clump 0 prefetch (younger than all W loads).
  const float* px[TOKW];
#pragma unroll
  for (int p = 0; p < TOKW; ++p)
    px[p] = x + (size_t)(tokBase + p) * DMODEL + sl * 4;

  float4 xa[TOKW], xb[TOKW];
#pragma unroll
  for (int p = 0; p < TOKW; ++p) xa[p] = *(const float4*)(px[p]);

  // Scatter half 0 to LDS; barrier 1 of 3.
#pragma unroll
  for (int k = 0; k < W4PT; ++k) {
    const int L = tid + k * TPB;
    const int e = L / 384, r = L - e * 384;
    sw4[(r >> 5) * 256 + e * 32 + (r & 31)] = wrA[k];
  }
  __syncthreads();

  float acc[TOKW][4];
#pragma unroll
  for (int p = 0; p < TOKW; ++p)
#pragma unroll
    for (int e = 0; e < 4; ++e) acc[p][e] = 0.f;

  // ---- half 0: stages 0..11 ----
#pragma unroll 1
  for (int s = 0; s < HALF; s += 2) {
    GATE_ITER(s, s);
  }

  // ---- restage: write half 1 (regs were loaded in prologue) ----
  __syncthreads();                  // all reads of half 0 done
#pragma unroll
  for (int k = 0; k < W4PT; ++k) {
    const int L = tid + k * TPB;
    const int e = L / 384, r = L - e * 384;
    sw4[(r >> 5) * 256 + e * 32 + (r & 31)] = wrB[k];
  }
  __syncthreads();

  // ---- half 1: stages 12..23 ----
#pragma unroll 1
  for (int s = 0; s < HALF; s += 2) {
    GATE_ITER(s, HALF + s);
  }

  // ---- reduce d-slices: butterfly over lane bits 1..5 ----
#pragma unroll
  for (int p = 0; p < TOKW; ++p)
#pragma unroll
    for (int e = 0; e < 4; ++e) {
      float v = acc[p][e];
      v += __shfl_xor(v, 2, 64);
      v += __shfl_xor(v, 4, 64);
      v += __shfl_xor(v, 8, 64);
      v += __shfl_xor(v, 16, 64);
      v += __shfl_xor(v, 32, 64);
      acc[p][e] = v;
    }
  // Now all lanes with equal tg hold identical acc (full-d sums).

  // ---- cross-tg expert-half exchange (lane p <-> p^1 for token p) ----
  float own[4], send[4];
#pragma unroll
  for (int p = 0; p < TOKW; ++p) {
    const bool isown  = (lane & 3) == p;
    const bool issend = ((lane ^ 1) & 3) == p;
#pragma unroll
    for (int e = 0; e < 4; ++e) {
      if (isown)  own[e]  = acc[p][e];
      if (issend) send[e] = acc[p][e];
    }
  }
  float other[4];
#pragma unroll
  for (int e = 0; e < 4; ++e) other[e] = __shfl_xor(send[e], 1, 64);

  if (lane < TOKW) {                // lane p owns token tokBase + p
    const float4 b0 = *(const float4*)bias;
    const float4 b1 = *(const float4*)(bias + 4);

    float l[NEXP];
    if ((lane & 1) == 0) {          // own = experts 0-3, other = 4-7
      l[0] = own[0] + b0.x;   l[1] = own[1] + b0.y;
      l[2] = own[2] + b0.z;   l[3] = own[3] + b0.w;
      l[4] = other[0] + b1.x; l[5] = other[1] + b1.y;
      l[6] = other[2] + b1.z; l[7] = other[3] + b1.w;
    } else {                        // own = experts 4-7, other = 0-3
      l[0] = other[0] + b0.x; l[1] = other[1] + b0.y;
      l[2] = other[2] + b0.z; l[3] = other[3] + b0.w;
      l[4] = own[0] + b1.x;   l[5] = own[1] + b1.y;
      l[6] = own[2] + b1.z;   l[7] = own[3] + b1.w;
    }

    float m = l[0];
#pragma unroll
    for (int e = 1; e < NEXP; ++e) m = fmaxf(m, l[e]);

    float p8[NEXP];
    float ssum = 0.f;
#pragma unroll
    for (int e = 0; e < NEXP; ++e) {
      p8[e] = expf(l[e] - m);
      ssum += p8[e];
    }
    const float inv = 1.f / ssum;
#pragma unroll
    for (int e = 0; e < NEXP; ++e) p8[e] *= inv;

    // top-2, first-occurrence on ties (matches jax.lax.top_k order).
    int i1 = 0;
    float v1 = p8[0];
#pragma unroll
    for (int e = 1; e < NEXP; ++e) {
      if (p8[e] > v1) { v1 = p8[e]; i1 = e; }
    }
    int i2 = -1;
    float v2 = -1.f;
#pragma unroll
    for (int e = 0; e < NEXP; ++e) {
      if (e == i1) continue;
      if (p8[e] > v2) { v2 = p8[e]; i2 = e; }
    }

    const float e2 = expf(v2 - v1);  // v1 >= v2
    const float r = 1.f / (1.f + e2);

    const int tok = tokBase + lane;
    *(float2*)(out + (size_t)tok * 2) = make_float2(r, e2 * r);
    *(float2*)(out + 2 * NTOK + (size_t)tok * 2) =
        make_float2((float)i1, (float)i2);
  }
}

extern "C" void kernel_launch(void* const* d_in, const int* in_sizes, int n_in,
                              void* d_out, int out_size, void* d_ws,
                              size_t ws_size, hipStream_t stream) {
  const float* x = (const float*)d_in[0];
  const float* W = (const float*)d_in[1];
  const float* b = (const float*)d_in[2];
  float* out = (float*)d_out;
  (void)d_ws; (void)ws_size;  // unused; poison fills are unconditional

  gate_fused6<<<dim3(NTOK / TOKB), TPB, 0, stream>>>(x, W, b, out);
}

// Round 7
// 281.795 us; speedup vs baseline: 1.0274x; 1.0274x over previous
//
#include <hip/hip_runtime.h>
#include <stdint.h>

// GatingLayer fused kernel, R10 = R7 (best known: 280.9 us), reverted
// after R9's W-in-LDS regression (289.5) falsified the W-cache theory.
// logits = x[16384,3072] . W[8,3072]^T + b[8]; softmax(8); top-2 (stable,
// lowest-index tie-break); softmax over the selected 2.
// d_out = values (fp32 x 32768) ++ indices-as-float (x 32768).
//
// Design: ZERO barriers, ZERO LDS, ZERO workspace, ONE kernel.
// W is register-double-buffered IN THE SAME PREFETCH CLUMP as x:
// compute(i) consumes only clump-i regs (older in vmcnt order than all
// of clump i+1), so the compiler's per-register vmcnt waits never drain
// the next prefetch (R4 lesson). No LDS staging: R9 proved the cache
// hierarchy serves W fine; LDS restaging cost -8.6 us (R5: -13 barriers).
// Occupancy: ~100 VGPR, __launch_bounds__(256,4) -> 4 waves/SIMD
// (R6 vs R7 showed occupancy is not binding; kept for the best config).
//
// Experiment ledger (dur_us totals; ~237 us = unconditional harness
// workspace-poison fills, proven untouchable in R4):
//   R3 split-kernel 286.7 | R4 global-W 307.2 | R5 LDS-13-barrier 293.1
//   R6 reg-clump TOKW=8 283.0 | R7 reg-clump TOKW=4 280.9 (BEST)
//   R9 LDS-2-half 289.5
//
// Lane map: lane = sl*2 + tg. sl in [0,32) = 16B d-slice of a 128-float
// stage; tg in [0,2) = expert half (tg=0 -> experts 0-3, else 4-7).
// Wave owns 4 tokens. Both tg lanes read the same x float4 (coalesces,
// no extra HBM traffic). acc[4][4] = 16 VGPRs. 24 stages of 128 d,
// ping-pong clumps {wa,xa}/{wb,xb}. Grid 1024 x 256 = 4 blocks/CU.

#define NTOK   16384
#define DMODEL 3072
#define NEXP   8
#define TPB    256              // 4 waves
#define TOKW   4                // tokens per wave
#define TOKB   16               // tokens per block
#define STF    128              // floats of d per stage
#define NST    (DMODEL / STF)   // 24 stages

#define GATE_COMPUTE(WR, XR)                                          \
  {                                                                   \
    _Pragma("unroll")                                                 \
    for (int p = 0; p < TOKW; ++p) {                                  \
      const float4 xv = XR[p];                                        \
      _Pragma("unroll")                                               \
      for (int e = 0; e < 4; ++e)                                     \
        acc[p][e] = fmaf(xv.x, WR[e].x,                               \
                    fmaf(xv.y, WR[e].y,                               \
                    fmaf(xv.z, WR[e].z,                               \
                    fmaf(xv.w, WR[e].w, acc[p][e]))));                \
    }                                                                 \
  }

__global__ __launch_bounds__(TPB, 4) void gate_fused4(
    const float* __restrict__ x, const float* __restrict__ W,
    const float* __restrict__ bias, float* __restrict__ out) {
  const int tid  = threadIdx.x;
  const int wv   = tid >> 6;
  const int lane = tid & 63;
  const int tg   = lane & 1;        // expert half
  const int sl   = lane >> 1;       // d-slice [0,32)
  const int tokBase = blockIdx.x * TOKB + wv * TOKW;

  // x: 4 token streams, this lane's 16B slice of each 128-float stage.
  const float* px[TOKW];
#pragma unroll
  for (int p = 0; p < TOKW; ++p)
    px[p] = x + (size_t)(tokBase + p) * DMODEL + sl * 4;

  // W: this lane's 4 experts (tg half), same 16B slice.
  const float* pw[4];
#pragma unroll
  for (int e = 0; e < 4; ++e)
    pw[e] = W + (size_t)(tg * 4 + e) * DMODEL + sl * 4;

  float acc[TOKW][4];
#pragma unroll
  for (int p = 0; p < TOKW; ++p)
#pragma unroll
    for (int e = 0; e < 4; ++e) acc[p][e] = 0.f;

  // ---- prologue: clump 0 (W + x together) ----
  float4 wa[4], wb[4], xa[TOKW], xb[TOKW];
#pragma unroll
  for (int e = 0; e < 4; ++e) wa[e] = *(const float4*)(pw[e]);
#pragma unroll
  for (int p = 0; p < TOKW; ++p) xa[p] = *(const float4*)(px[p]);

#pragma unroll 1
  for (int s = 0; s < NST; s += 2) {
    // prefetch clump s+1
#pragma unroll
    for (int e = 0; e < 4; ++e)
      wb[e] = *(const float4*)(pw[e] + (s + 1) * STF);
#pragma unroll
    for (int p = 0; p < TOKW; ++p)
      xb[p] = *(const float4*)(px[p] + (s + 1) * STF);

    GATE_COMPUTE(wa, xa);           // consumes clump s only

    if (s + 2 < NST) {              // prefetch clump s+2
#pragma unroll
      for (int e = 0; e < 4; ++e)
        wa[e] = *(const float4*)(pw[e] + (s + 2) * STF);
#pragma unroll
      for (int p = 0; p < TOKW; ++p)
        xa[p] = *(const float4*)(px[p] + (s + 2) * STF);
    }

    GATE_COMPUTE(wb, xb);           // consumes clump s+1 only
  }

  // ---- reduce d-slices: butterfly over lane bits 1..5 ----
#pragma unroll
  for (int p = 0; p < TOKW; ++p)
#pragma unroll
    for (int e = 0; e < 4; ++e) {
      float v = acc[p][e];
      v += __shfl_xor(v, 2, 64);
      v += __shfl_xor(v, 4, 64);
      v += __shfl_xor(v, 8, 64);
      v += __shfl_xor(v, 16, 64);
      v += __shfl_xor(v, 32, 64);
      acc[p][e] = v;
    }
  // Now all lanes with equal tg hold identical acc (full-d sums).

  // ---- cross-tg expert-half exchange (lane p <-> p^1 for token p) ----
  // own[e]  = acc[lane&3][e]      (this lane's token, its expert half)
  // send[e] = acc[(lane^1)&3][e]  (partner's token, this expert half)
  float own[4], send[4];
#pragma unroll
  for (int p = 0; p < TOKW; ++p) {
    const bool isown  = (lane & 3) == p;
    const bool issend = ((lane ^ 1) & 3) == p;
#pragma unroll
    for (int e = 0; e < 4; ++e) {
      if (isown)  own[e]  = acc[p][e];
      if (issend) send[e] = acc[p][e];
    }
  }
  float other[4];
#pragma unroll
  for (int e = 0; e < 4; ++e) other[e] = __shfl_xor(send[e], 1, 64);

  if (lane < TOKW) {                // lane p owns token tokBase + p
    const float4 b0 = *(const float4*)bias;
    const float4 b1 = *(const float4*)(bias + 4);

    float l[NEXP];
    if ((lane & 1) == 0) {          // own = experts 0-3, other = 4-7
      l[0] = own[0] + b0.x;   l[1] = own[1] + b0.y;
      l[2] = own[2] + b0.z;   l[3] = own[3] + b0.w;
      l[4] = other[0] + b1.x; l[5] = other[1] + b1.y;
      l[6] = other[2] + b1.z; l[7] = other[3] + b1.w;
    } else {                        // own = experts 4-7, other = 0-3
      l[0] = other[0] + b0.x; l[1] = other[1] + b0.y;
      l[2] = other[2] + b0.z; l[3] = other[3] + b0.w;
      l[4] = own[0] + b1.x;   l[5] = own[1] + b1.y;
      l[6] = own[2] + b1.z;   l[7] = own[3] + b1.w;
    }

    float m = l[0];
#pragma unroll
    for (int e = 1; e < NEXP; ++e) m = fmaxf(m, l[e]);

    float p8[NEXP];
    float ssum = 0.f;
#pragma unroll
    for (int e = 0; e < NEXP; ++e) {
      p8[e] = expf(l[e] - m);
      ssum += p8[e];
    }
    const float inv = 1.f / ssum;
#pragma unroll
    for (int e = 0; e < NEXP; ++e) p8[e] *= inv;

    // top-2, first-occurrence on ties (matches jax.lax.top_k order).
    int i1 = 0;
    float v1 = p8[0];
#pragma unroll
    for (int e = 1; e < NEXP; ++e) {
      if (p8[e] > v1) { v1 = p8[e]; i1 = e; }
    }
    int i2 = -1;
    float v2 = -1.f;
#pragma unroll
    for (int e = 0; e < NEXP; ++e) {
      if (e == i1) continue;
      if (p8[e] > v2) { v2 = p8[e]; i2 = e; }
    }

    const float e2 = expf(v2 - v1);  // v1 >= v2
    const float r = 1.f / (1.f + e2);

    const int tok = tokBase + lane;
    *(float2*)(out + (size_t)tok * 2) = make_float2(r, e2 * r);
    *(float2*)(out + 2 * NTOK + (size_t)tok * 2) =
        make_float2((float)i1, (float)i2);
  }
}

extern "C" void kernel_launch(void* const* d_in, const int* in_sizes, int n_in,
                              void* d_out, int out_size, void* d_ws,
                              size_t ws_size, hipStream_t stream) {
  const float* x = (const float*)d_in[0];
  const float* W = (const float*)d_in[1];
  const float* b = (const float*)d_in[2];
  float* out = (float*)d_out;
  (void)d_ws; (void)ws_size;  // unused; poison fills are unconditional

  gate_fused4<<<dim3(NTOK / TOKB), TPB, 0, stream>>>(x, W, b, out);
}